// Round 5
// baseline (359.390 us; speedup 1.0000x reference)
//
#include <hip/hip_runtime.h>
#include <hip/hip_bf16.h>
#include <math.h>

#define FH 128   // feature width of x and all hidden layers

typedef __attribute__((ext_vector_type(8))) short short8v;   // 8 bf16 (4 VGPRs)
typedef __attribute__((ext_vector_type(4))) float float4v;
typedef unsigned short ushort_t;
typedef unsigned int   uint32;

__device__ __forceinline__ ushort_t f2bf(float f) {          // RNE float->bf16
    uint32 u = __builtin_bit_cast(uint32, f);
    u += 0x7fffu + ((u >> 16) & 1u);
    return (ushort_t)(u >> 16);
}
__device__ __forceinline__ float bf_lo(uint32 w) { return __builtin_bit_cast(float, w << 16); }
__device__ __forceinline__ float bf_hi(uint32 w) { return __builtin_bit_cast(float, w & 0xffff0000u); }

// ---------------------------------------------------------------------------
// prep: fp32->bf16 convert of x  +  3 weight packs, one kernel.
// pack: Bp[((nt*8+kt)*64 + lane)*8 + j] = W[k][n],
//   nt=n>>4, kt=k>>5, lane=(n&15)+16*((k>>3)&3), j=k&7   (W = [Wl;Wr], 256x128)
__device__ __forceinline__ void pack_one(const float* __restrict__ Wl,
                                         const float* __restrict__ Wr,
                                         ushort_t* __restrict__ Bp, int t) {
    int k = t >> 7, n = t & 127;
    float v = (k < FH) ? Wl[k * FH + n] : Wr[(k - FH) * FH + n];
    int nt = n >> 4, kt = k >> 5;
    int lane = (n & 15) + (((k >> 3) & 3) << 4);
    int j = k & 7;
    Bp[(((nt * 8 + kt) * 64) + lane) * 8 + j] = f2bf(v);
}

__global__ __launch_bounds__(256) void prep_kernel(const float* __restrict__ x,
                                                   ushort_t* __restrict__ xb, size_t n,
                                                   int cvtBlocks,
                                                   const float* __restrict__ Wl1, const float* __restrict__ Wr1, ushort_t* __restrict__ Bp1,
                                                   const float* __restrict__ Wl2, const float* __restrict__ Wr2, ushort_t* __restrict__ Bp2,
                                                   const float* __restrict__ Wl3, const float* __restrict__ Wr3, ushort_t* __restrict__ Bp3) {
    int b = blockIdx.x;
    if (b < cvtBlocks) {
        size_t base = ((size_t)b * 256 + threadIdx.x) * 8;
        if (base >= n) return;
        const float4 a = *(const float4*)(x + base);
        const float4 c = *(const float4*)(x + base + 4);
        ushort_t o[8] = {f2bf(a.x), f2bf(a.y), f2bf(a.z), f2bf(a.w),
                         f2bf(c.x), f2bf(c.y), f2bf(c.z), f2bf(c.w)};
        *(uint4*)(xb + base) = *(const uint4*)o;
    } else {
        int pb = b - cvtBlocks;                 // 0..383
        int which = pb >> 7;                    // 0..2
        int t = (pb & 127) * 256 + threadIdx.x; // 0..32767
        if (which == 0)      pack_one(Wl1, Wr1, Bp1, t);
        else if (which == 1) pack_one(Wl2, Wr2, Bp2, t);
        else                 pack_one(Wl3, Wr3, Bp3, t);
    }
}

// ---------------------------------------------------------------------------
// CSR build
__global__ __launch_bounds__(256) void deg_kernel(const int* __restrict__ dst,
                                                  int* __restrict__ deg, int E) {
    int e = blockIdx.x * 256 + threadIdx.x;
    if (e < E) atomicAdd(&deg[dst[e]], 1);
}

__global__ __launch_bounds__(256) void scan1_kernel(const int* __restrict__ deg,
                                                    int* __restrict__ rowptr,
                                                    int* __restrict__ blockSums, int N) {
    __shared__ int lds[256];
    const int base = blockIdx.x * 1024;
    const int t = threadIdx.x;
    int v[4]; int sum = 0;
    #pragma unroll
    for (int j = 0; j < 4; ++j) {
        int idx = base + t * 4 + j;
        v[j] = (idx < N) ? deg[idx] : 0;
        sum += v[j];
    }
    lds[t] = sum; __syncthreads();
    for (int off = 1; off < 256; off <<= 1) {
        int val = lds[t];
        int add = (t >= off) ? lds[t - off] : 0;
        __syncthreads();
        lds[t] = val + add;
        __syncthreads();
    }
    int run = (t > 0) ? lds[t - 1] : 0;
    #pragma unroll
    for (int j = 0; j < 4; ++j) {
        int idx = base + t * 4 + j;
        if (idx < N) rowptr[idx] = run;
        run += v[j];
    }
    if (t == 255) blockSums[blockIdx.x] = lds[255];
}

__global__ void scan2_kernel(int* __restrict__ blockSums, int* __restrict__ rowptr,
                             int nb, int N) {
    if (threadIdx.x == 0 && blockIdx.x == 0) {
        int carry = 0;
        for (int i = 0; i < nb; ++i) {
            int s = blockSums[i];
            blockSums[i] = carry;
            carry += s;
        }
        rowptr[N] = carry;   // == E
    }
}

// adds block offset AND writes pos[] (atomic cursor copy) in one pass
__global__ __launch_bounds__(256) void scan3_kernel(int* __restrict__ rowptr,
                                                    int* __restrict__ pos,
                                                    const int* __restrict__ blockSums, int N) {
    const int base = blockIdx.x * 1024;
    const int add = blockSums[blockIdx.x];
    #pragma unroll
    for (int j = 0; j < 4; ++j) {
        int idx = base + threadIdx.x * 4 + j;
        if (idx < N) {
            int v = rowptr[idx] + add;
            rowptr[idx] = v;
            pos[idx] = v;
        }
    }
}

__global__ __launch_bounds__(256) void fill_csr_kernel(const int* __restrict__ src,
                                                       const int* __restrict__ dst,
                                                       int* __restrict__ pos,
                                                       int* __restrict__ csr, int E) {
    int e = blockIdx.x * 256 + threadIdx.x;
    if (e >= E) return;
    int idx = atomicAdd(&pos[dst[e]], 1);
    csr[idx] = src[e];
}

// ---------------------------------------------------------------------------
// batch is SORTED: gstart[g] = lower_bound(batch, g); gstart[G] = N
__global__ __launch_bounds__(256) void group_bounds_kernel(const int* __restrict__ batch,
                                                           int* __restrict__ gstart,
                                                           int N, int G) {
    int g = blockIdx.x * 256 + threadIdx.x;
    if (g > G) return;
    int lo = 0, hi = N;
    while (lo < hi) {
        int mid = (lo + hi) >> 1;
        if (batch[mid] < g) lo = mid + 1; else hi = mid;
    }
    gstart[g] = lo;
}

// ---------------------------------------------------------------------------
// FUSED SAGE layer: gather-mean (CSR pull) + MFMA GEMM + bias + ReLU.
// Block = 256 threads = 4 waves; 64 output rows/block (16 per wave).
// LDS (32KB) is time-shared: phase A/B use it as sAg[64][128] bf16 (16KB,
// wave-private rows); phase C re-uses it as the 32KB B-chunk (4 of 8 nt).
// NOT in-place safe (blocks gather arbitrary rows) -> ping-pong h buffers.
__global__ __launch_bounds__(256) void fused_sage_kernel(const ushort_t* __restrict__ xin,
                                                         const int* __restrict__ rowptr,
                                                         const int* __restrict__ csr,
                                                         const ushort_t* __restrict__ Bp,
                                                         const float* __restrict__ bl,
                                                         ushort_t* __restrict__ out, int M) {
    __shared__ ushort_t smem[16384];   // 32 KB
    const int tid  = threadIdx.x;
    const int wave = tid >> 6;
    const int lane = tid & 63;
    const int half = lane >> 5;        // which edge of the pair
    const int c    = lane & 31;        // uint2 column (8B = 4 bf16)
    const int grp  = lane >> 4;
    const int rowBase = blockIdx.x * 64 + wave * 16;

    // ---- phase A: gather-mean 16 rows into sAg (wave-private region)
    for (int r = 0; r < 16; ++r) {
        const int row = rowBase + r;          // wave-uniform
        if (row >= M) break;
        const int beg = rowptr[row], end = rowptr[row + 1];
        const uint32* xp = (const uint32*)xin + c * 2;
        float a0 = 0.f, a1 = 0.f, a2 = 0.f, a3 = 0.f;
        for (int i = beg + half; i < end; i += 2) {
            const int s = csr[i];
            const uint2 w = *(const uint2*)(xp + (size_t)s * 64);
            a0 += bf_lo(w.x); a1 += bf_hi(w.x);
            a2 += bf_lo(w.y); a3 += bf_hi(w.y);
        }
        a0 += __shfl_xor(a0, 32);
        a1 += __shfl_xor(a1, 32);
        a2 += __shfl_xor(a2, 32);
        a3 += __shfl_xor(a3, 32);
        if (half == 0) {
            const float inv = 1.0f / (float)max(end - beg, 1);
            uint2 o;
            o.x = (uint32)f2bf(a0 * inv) | ((uint32)f2bf(a1 * inv) << 16);
            o.y = (uint32)f2bf(a2 * inv) | ((uint32)f2bf(a3 * inv) << 16);
            *(uint2*)&smem[(wave * 16 + r) * FH + c * 4] = o;
        }
    }
    __syncthreads();   // (paranoia: sAg writes visible; regions are wave-private)

    // ---- phase B: build A fragments (aggr from LDS, xin direct from global)
    const int arow = min(rowBase + (lane & 15), M - 1);
    const ushort_t* myrow = &smem[(wave * 16 + (lane & 15)) * FH];
    short8v afrag[8];
    #pragma unroll
    for (int kt = 0; kt < 4; ++kt)
        afrag[kt] = *(const short8v*)(myrow + kt * 32 + grp * 8);
    #pragma unroll
    for (int kt = 0; kt < 4; ++kt)
        afrag[4 + kt] = *(const short8v*)(xin + (size_t)arow * FH + kt * 32 + grp * 8);

    // ---- phase C: 2 chunks x (stage 32KB B + 4 nt x 8 kt MFMA + epilogue)
    #pragma unroll
    for (int ch = 0; ch < 2; ++ch) {
        __syncthreads();               // all waves done reading smem
        {
            const uint4* s = (const uint4*)Bp + ch * 2048;   // 32KB chunk
            uint4* d = (uint4*)smem;
            #pragma unroll
            for (int i = 0; i < 8; ++i)
                d[tid + 256 * i] = s[tid + 256 * i];
        }
        __syncthreads();
        #pragma unroll
        for (int ntl = 0; ntl < 4; ++ntl) {
            const int nt = ch * 4 + ntl;
            float4v acc = {0.f, 0.f, 0.f, 0.f};
            #pragma unroll
            for (int kt = 0; kt < 8; ++kt) {
                const short8v b = *(const short8v*)(smem + (((ntl * 8 + kt) * 64) + lane) * 8);
                acc = __builtin_amdgcn_mfma_f32_16x16x32_bf16(afrag[kt], b, acc, 0, 0, 0);
            }
            const int col = nt * 16 + (lane & 15);
            const float bias = bl[col];
            #pragma unroll
            for (int r = 0; r < 4; ++r) {
                const int row = rowBase + grp * 4 + r;
                if (row < M)
                    out[(size_t)row * FH + col] = f2bf(fmaxf(acc[r] + bias, 0.f));
            }
        }
    }
}

// ---------------------------------------------------------------------------
// fused head: per-group mean pool -> relu(gmean@W4+b4) -> log_softmax(g2@W5+b5)
__global__ __launch_bounds__(256) void head_kernel(const ushort_t* __restrict__ h,
                                                   const int* __restrict__ gstart,
                                                   const float* __restrict__ W4,
                                                   const float* __restrict__ b4,
                                                   const float* __restrict__ W5,
                                                   const float* __restrict__ b5,
                                                   float* __restrict__ out, int G) {
    __shared__ float sred[4][FH];
    __shared__ float sg2[64];
    __shared__ float sl[10];
    __shared__ float slse;
    const int g = blockIdx.x;
    const int t = threadIdx.x;
    const int wave = t >> 6, lane = t & 63;
    const int beg = gstart[g], end = gstart[g + 1];

    const uint32* hp = (const uint32*)h + lane;
    float a0 = 0.f, a1 = 0.f;
    for (int i = beg + wave; i < end; i += 4) {
        const uint32 w = hp[(size_t)i * 64];
        a0 += bf_lo(w); a1 += bf_hi(w);
    }
    sred[wave][lane * 2]     = a0;
    sred[wave][lane * 2 + 1] = a1;
    __syncthreads();
    if (t < FH) {
        const float s = sred[0][t] + sred[1][t] + sred[2][t] + sred[3][t];
        sred[0][t] = s / (float)max(end - beg, 1);   // gmean
    }
    __syncthreads();
    if (t < 64) {
        float acc = b4[t];
        #pragma unroll 4
        for (int k = 0; k < FH; ++k)
            acc += sred[0][k] * W4[k * 64 + t];
        sg2[t] = fmaxf(acc, 0.f);
    }
    __syncthreads();
    if (t < 10) {
        float acc = b5[t];
        #pragma unroll 4
        for (int k = 0; k < 64; ++k)
            acc += sg2[k] * W5[k * 10 + t];
        sl[t] = acc;
    }
    __syncthreads();
    if (t == 0) {
        float m = sl[0];
        #pragma unroll
        for (int j = 1; j < 10; ++j) m = fmaxf(m, sl[j]);
        float s = 0.f;
        #pragma unroll
        for (int j = 0; j < 10; ++j) s += expf(sl[j] - m);
        slse = m + logf(s);
    }
    __syncthreads();
    if (t < 10) out[g * 10 + t] = sl[t] - slse;
}

// ---------------------------------------------------------------------------
extern "C" void kernel_launch(void* const* d_in, const int* in_sizes, int n_in,
                              void* d_out, int out_size, void* d_ws, size_t ws_size,
                              hipStream_t stream) {
    const float* x     = (const float*)d_in[0];
    const int*   ei    = (const int*)d_in[1];
    const int*   batch = (const int*)d_in[2];
    const float* Wl1 = (const float*)d_in[3];
    const float* bl1 = (const float*)d_in[4];
    const float* Wr1 = (const float*)d_in[5];
    const float* Wl2 = (const float*)d_in[6];
    const float* bl2 = (const float*)d_in[7];
    const float* Wr2 = (const float*)d_in[8];
    const float* Wl3 = (const float*)d_in[9];
    const float* bl3 = (const float*)d_in[10];
    const float* Wr3 = (const float*)d_in[11];
    const float* W4  = (const float*)d_in[12];
    const float* b4  = (const float*)d_in[13];
    const float* W5  = (const float*)d_in[14];
    const float* b5  = (const float*)d_in[15];
    float* out = (float*)d_out;

    const int N = in_sizes[0] / FH;   // 50000
    const int E = in_sizes[1] / 2;    // 600000
    const int G = out_size / 10;      // 500
    const int* src = ei;
    const int* dst = ei + E;

    // ---- workspace layout (256B-aligned chunks)
    char* p = (char*)d_ws;
    auto take = [&](size_t bytes) { char* q = p; p += (bytes + 255) & ~(size_t)255; return q; };
    ushort_t* xb    = (ushort_t*)take((size_t)N * FH * 2);
    ushort_t* hA    = (ushort_t*)take((size_t)N * FH * 2);
    ushort_t* hB    = (ushort_t*)take((size_t)N * FH * 2);
    int* deg        = (int*)take((size_t)N * 4);
    int* rowptr     = (int*)take((size_t)(N + 1) * 4);
    int* pos        = (int*)take((size_t)N * 4);
    int* csr        = (int*)take((size_t)E * 4);
    int* blockSums  = (int*)take(256 * 4);
    ushort_t* Bp1   = (ushort_t*)take(256 * FH * 2);
    ushort_t* Bp2   = (ushort_t*)take(256 * FH * 2);
    ushort_t* Bp3   = (ushort_t*)take(256 * FH * 2);
    int* gstart     = (int*)take((size_t)(G + 1) * 4);

    const int nb = (N + 1023) / 1024;

    hipMemsetAsync(deg, 0, (size_t)N * 4, stream);

    // ---- prep: cvt x->bf16 + pack 3 weight sets (one kernel)
    const int cvtBlocks = (int)(((size_t)N * FH / 8 + 255) / 256);
    prep_kernel<<<cvtBlocks + 384, 256, 0, stream>>>(x, xb, (size_t)N * FH, cvtBlocks,
                                                     Wl1, Wr1, Bp1, Wl2, Wr2, Bp2, Wl3, Wr3, Bp3);

    // ---- CSR build
    deg_kernel<<<(E + 255) / 256, 256, 0, stream>>>(dst, deg, E);
    scan1_kernel<<<nb, 256, 0, stream>>>(deg, rowptr, blockSums, N);
    scan2_kernel<<<1, 64, 0, stream>>>(blockSums, rowptr, nb, N);
    scan3_kernel<<<nb, 256, 0, stream>>>(rowptr, pos, blockSums, N);
    fill_csr_kernel<<<(E + 255) / 256, 256, 0, stream>>>(src, dst, pos, csr, E);

    // ---- group bounds from sorted batch
    group_bounds_kernel<<<(G + 256) / 256, 256, 0, stream>>>(batch, gstart, N, G);

    const int layerGrid = (N + 63) / 64;

    // ---- 3 fused SAGE layers (ping-pong: xb->hA->hB->hA)
    fused_sage_kernel<<<layerGrid, 256, 0, stream>>>(xb, rowptr, csr, Bp1, bl1, hA, N);
    fused_sage_kernel<<<layerGrid, 256, 0, stream>>>(hA, rowptr, csr, Bp2, bl2, hB, N);
    fused_sage_kernel<<<layerGrid, 256, 0, stream>>>(hB, rowptr, csr, Bp3, bl3, hA, N);

    // ---- fused head (pool + MLP + log_softmax)
    head_kernel<<<G, 256, 0, stream>>>(hA, gstart, W4, b4, W5, b5, out, G);
}

// Round 6
// 242.901 us; speedup vs baseline: 1.4796x; 1.4796x over previous
//
#include <hip/hip_runtime.h>
#include <hip/hip_bf16.h>
#include <math.h>

#define FH 128   // feature width of x and all hidden layers

typedef __attribute__((ext_vector_type(8))) short short8v;   // 8 bf16 (4 VGPRs)
typedef __attribute__((ext_vector_type(4))) float float4v;
typedef unsigned short ushort_t;
typedef unsigned int   uint32;

__device__ __forceinline__ ushort_t f2bf(float f) {          // RNE float->bf16
    uint32 u = __builtin_bit_cast(uint32, f);
    u += 0x7fffu + ((u >> 16) & 1u);
    return (ushort_t)(u >> 16);
}
__device__ __forceinline__ float bf_lo(uint32 w) { return __builtin_bit_cast(float, w << 16); }
__device__ __forceinline__ float bf_hi(uint32 w) { return __builtin_bit_cast(float, w & 0xffff0000u); }
__device__ __forceinline__ uint32 pack2(float lo, float hi) {
    return (uint32)f2bf(lo) | ((uint32)f2bf(hi) << 16);
}

// ---------------------------------------------------------------------------
// prep: fp32->bf16 convert of x  +  3 weight packs, one kernel.
// pack: Bp[((nt*8+kt)*64 + lane)*8 + j] = W[k][n],
//   nt=n>>4, kt=k>>5, lane=(n&15)+16*((k>>3)&3), j=k&7   (W = [Wl;Wr], 256x128)
__device__ __forceinline__ void pack_one(const float* __restrict__ Wl,
                                         const float* __restrict__ Wr,
                                         ushort_t* __restrict__ Bp, int t) {
    int k = t >> 7, n = t & 127;
    float v = (k < FH) ? Wl[k * FH + n] : Wr[(k - FH) * FH + n];
    int nt = n >> 4, kt = k >> 5;
    int lane = (n & 15) + (((k >> 3) & 3) << 4);
    int j = k & 7;
    Bp[(((nt * 8 + kt) * 64) + lane) * 8 + j] = f2bf(v);
}

__global__ __launch_bounds__(256) void prep_kernel(const float* __restrict__ x,
                                                   ushort_t* __restrict__ xb, size_t n,
                                                   int cvtBlocks,
                                                   const float* __restrict__ Wl1, const float* __restrict__ Wr1, ushort_t* __restrict__ Bp1,
                                                   const float* __restrict__ Wl2, const float* __restrict__ Wr2, ushort_t* __restrict__ Bp2,
                                                   const float* __restrict__ Wl3, const float* __restrict__ Wr3, ushort_t* __restrict__ Bp3) {
    int b = blockIdx.x;
    if (b < cvtBlocks) {
        size_t base = ((size_t)b * 256 + threadIdx.x) * 8;
        if (base >= n) return;
        const float4 a = *(const float4*)(x + base);
        const float4 c = *(const float4*)(x + base + 4);
        ushort_t o[8] = {f2bf(a.x), f2bf(a.y), f2bf(a.z), f2bf(a.w),
                         f2bf(c.x), f2bf(c.y), f2bf(c.z), f2bf(c.w)};
        *(uint4*)(xb + base) = *(const uint4*)o;
    } else {
        int pb = b - cvtBlocks;                 // 0..383
        int which = pb >> 7;                    // 0..2
        int t = (pb & 127) * 256 + threadIdx.x; // 0..32767
        if (which == 0)      pack_one(Wl1, Wr1, Bp1, t);
        else if (which == 1) pack_one(Wl2, Wr2, Bp2, t);
        else                 pack_one(Wl3, Wr3, Bp3, t);
    }
}

// ---------------------------------------------------------------------------
// CSR build
__global__ __launch_bounds__(256) void deg_kernel(const int* __restrict__ dst,
                                                  int* __restrict__ deg, int E) {
    int e = blockIdx.x * 256 + threadIdx.x;
    if (e < E) atomicAdd(&deg[dst[e]], 1);
}

__global__ __launch_bounds__(256) void scan1_kernel(const int* __restrict__ deg,
                                                    int* __restrict__ rowptr,
                                                    int* __restrict__ blockSums, int N) {
    __shared__ int lds[256];
    const int base = blockIdx.x * 1024;
    const int t = threadIdx.x;
    int v[4]; int sum = 0;
    #pragma unroll
    for (int j = 0; j < 4; ++j) {
        int idx = base + t * 4 + j;
        v[j] = (idx < N) ? deg[idx] : 0;
        sum += v[j];
    }
    lds[t] = sum; __syncthreads();
    for (int off = 1; off < 256; off <<= 1) {
        int val = lds[t];
        int add = (t >= off) ? lds[t - off] : 0;
        __syncthreads();
        lds[t] = val + add;
        __syncthreads();
    }
    int run = (t > 0) ? lds[t - 1] : 0;
    #pragma unroll
    for (int j = 0; j < 4; ++j) {
        int idx = base + t * 4 + j;
        if (idx < N) rowptr[idx] = run;
        run += v[j];
    }
    if (t == 255) blockSums[blockIdx.x] = lds[255];
}

__global__ void scan2_kernel(int* __restrict__ blockSums, int* __restrict__ rowptr,
                             int nb, int N) {
    if (threadIdx.x == 0 && blockIdx.x == 0) {
        int carry = 0;
        for (int i = 0; i < nb; ++i) {
            int s = blockSums[i];
            blockSums[i] = carry;
            carry += s;
        }
        rowptr[N] = carry;   // == E
    }
}

// adds block offset AND writes pos[] (atomic cursor copy) in one pass
__global__ __launch_bounds__(256) void scan3_kernel(int* __restrict__ rowptr,
                                                    int* __restrict__ pos,
                                                    const int* __restrict__ blockSums, int N) {
    const int base = blockIdx.x * 1024;
    const int add = blockSums[blockIdx.x];
    #pragma unroll
    for (int j = 0; j < 4; ++j) {
        int idx = base + threadIdx.x * 4 + j;
        if (idx < N) {
            int v = rowptr[idx] + add;
            rowptr[idx] = v;
            pos[idx] = v;
        }
    }
}

__global__ __launch_bounds__(256) void fill_csr_kernel(const int* __restrict__ src,
                                                       const int* __restrict__ dst,
                                                       int* __restrict__ pos,
                                                       int* __restrict__ csr, int E) {
    int e = blockIdx.x * 256 + threadIdx.x;
    if (e >= E) return;
    int idx = atomicAdd(&pos[dst[e]], 1);
    csr[idx] = src[e];
}

// ---------------------------------------------------------------------------
// batch is SORTED: gstart[g] = lower_bound(batch, g); gstart[G] = N
__global__ __launch_bounds__(256) void group_bounds_kernel(const int* __restrict__ batch,
                                                           int* __restrict__ gstart,
                                                           int N, int G) {
    int g = blockIdx.x * 256 + threadIdx.x;
    if (g > G) return;
    int lo = 0, hi = N;
    while (lo < hi) {
        int mid = (lo + hi) >> 1;
        if (batch[mid] < g) lo = mid + 1; else hi = mid;
    }
    gstart[g] = lo;
}

// ---------------------------------------------------------------------------
// pull aggregation (bf16 in/out, fp32 accumulate): one wave per dst node.
// 4 edges in flight (16-lane groups, uint4 = full 256B row per group),
// manually unrolled 2-deep -> up to 8 outstanding row reads per wave.
__global__ __launch_bounds__(256) void pull_mean_kernel(const ushort_t* __restrict__ x,
                                                        const int* __restrict__ rowptr,
                                                        const int* __restrict__ csr,
                                                        ushort_t* __restrict__ aggr, int N) {
    const int v = (blockIdx.x * 256 + threadIdx.x) >> 6;
    if (v >= N) return;
    const int lane = threadIdx.x & 63;
    const int grp  = lane >> 4;        // which of 4 concurrent edges
    const int li   = lane & 15;        // uint4 column within the row
    const int beg = rowptr[v], end = rowptr[v + 1];
    const uint4* xp = (const uint4*)x + li;    // row = 16 uint4 (256B)

    float a0 = 0.f, a1 = 0.f, a2 = 0.f, a3 = 0.f;
    float a4 = 0.f, a5 = 0.f, a6 = 0.f, a7 = 0.f;

    int i = beg + grp;
    for (; i + 4 < end; i += 8) {
        const int s0 = csr[i];
        const int s1 = csr[i + 4];
        const uint4 w0 = xp[(size_t)s0 * 16];
        const uint4 w1 = xp[(size_t)s1 * 16];
        a0 += bf_lo(w0.x); a1 += bf_hi(w0.x); a2 += bf_lo(w0.y); a3 += bf_hi(w0.y);
        a4 += bf_lo(w0.z); a5 += bf_hi(w0.z); a6 += bf_lo(w0.w); a7 += bf_hi(w0.w);
        a0 += bf_lo(w1.x); a1 += bf_hi(w1.x); a2 += bf_lo(w1.y); a3 += bf_hi(w1.y);
        a4 += bf_lo(w1.z); a5 += bf_hi(w1.z); a6 += bf_lo(w1.w); a7 += bf_hi(w1.w);
    }
    if (i < end) {
        const int s0 = csr[i];
        const uint4 w0 = xp[(size_t)s0 * 16];
        a0 += bf_lo(w0.x); a1 += bf_hi(w0.x); a2 += bf_lo(w0.y); a3 += bf_hi(w0.y);
        a4 += bf_lo(w0.z); a5 += bf_hi(w0.z); a6 += bf_lo(w0.w); a7 += bf_hi(w0.w);
    }

    // combine the 4 group partials (feature li*8.. lives in lanes li, li+16, li+32, li+48)
    a0 += __shfl_xor(a0, 16); a1 += __shfl_xor(a1, 16);
    a2 += __shfl_xor(a2, 16); a3 += __shfl_xor(a3, 16);
    a4 += __shfl_xor(a4, 16); a5 += __shfl_xor(a5, 16);
    a6 += __shfl_xor(a6, 16); a7 += __shfl_xor(a7, 16);
    a0 += __shfl_xor(a0, 32); a1 += __shfl_xor(a1, 32);
    a2 += __shfl_xor(a2, 32); a3 += __shfl_xor(a3, 32);
    a4 += __shfl_xor(a4, 32); a5 += __shfl_xor(a5, 32);
    a6 += __shfl_xor(a6, 32); a7 += __shfl_xor(a7, 32);

    if (grp == 0) {
        const float inv = 1.0f / (float)max(end - beg, 1);
        uint4 o;
        o.x = pack2(a0 * inv, a1 * inv);
        o.y = pack2(a2 * inv, a3 * inv);
        o.z = pack2(a4 * inv, a5 * inv);
        o.w = pack2(a6 * inv, a7 * inv);
        ((uint4*)aggr)[(size_t)v * 16 + li] = o;
    }
}

// ---------------------------------------------------------------------------
// fused SAGE layer via MFMA: out = relu([aggr|xin](Mx256) @ W(256x128) + bl)
// 4 waves/block, 16 rows/wave; full weight tile staged in LDS (64KB).
// In-place safe: rows are loaded to registers before any store; rows are
// wave-exclusive and out[row] depends only on row's own inputs.
__global__ __launch_bounds__(256) void sage_mfma_kernel(const ushort_t* __restrict__ xin,
                                                        const ushort_t* __restrict__ aggr,
                                                        const ushort_t* __restrict__ Bp,
                                                        const float* __restrict__ bl,
                                                        ushort_t* __restrict__ out, int M) {
    __shared__ ushort_t sB[8 * 8 * 64 * 8];   // 64 KB
    const int tid = threadIdx.x;
    {   // cooperative 64KB load: 4096 x 16B
        const uint4* s = (const uint4*)Bp;
        uint4* d = (uint4*)sB;
        #pragma unroll
        for (int i = 0; i < 16; ++i)
            d[tid + 256 * i] = s[tid + 256 * i];
    }
    __syncthreads();

    const int wave = tid >> 6;
    const int lane = tid & 63;
    const int grp  = lane >> 4;
    const int rowBase = (blockIdx.x * 4 + wave) * 16;
    if (rowBase >= M) return;
    const int arow = min(rowBase + (lane & 15), M - 1);

    short8v afrag[8];
    #pragma unroll
    for (int kt = 0; kt < 4; ++kt)
        afrag[kt] = *(const short8v*)(aggr + (size_t)arow * FH + kt * 32 + grp * 8);
    #pragma unroll
    for (int kt = 0; kt < 4; ++kt)
        afrag[4 + kt] = *(const short8v*)(xin + (size_t)arow * FH + kt * 32 + grp * 8);

    #pragma unroll
    for (int nt = 0; nt < 8; ++nt) {
        float4v acc = {0.f, 0.f, 0.f, 0.f};
        #pragma unroll
        for (int kt = 0; kt < 8; ++kt) {
            const short8v b = *(const short8v*)(sB + (((nt * 8 + kt) * 64) + lane) * 8);
            acc = __builtin_amdgcn_mfma_f32_16x16x32_bf16(afrag[kt], b, acc, 0, 0, 0);
        }
        const int col = nt * 16 + (lane & 15);
        const float bias = bl[col];
        #pragma unroll
        for (int r = 0; r < 4; ++r) {
            const int row = rowBase + grp * 4 + r;
            if (row < M)
                out[(size_t)row * FH + col] = f2bf(fmaxf(acc[r] + bias, 0.f));
        }
    }
}

// ---------------------------------------------------------------------------
// fused head: per-group mean pool -> relu(gmean@W4+b4) -> log_softmax(g2@W5+b5)
__global__ __launch_bounds__(256) void head_kernel(const ushort_t* __restrict__ h,
                                                   const int* __restrict__ gstart,
                                                   const float* __restrict__ W4,
                                                   const float* __restrict__ b4,
                                                   const float* __restrict__ W5,
                                                   const float* __restrict__ b5,
                                                   float* __restrict__ out, int G) {
    __shared__ float sred[4][FH];
    __shared__ float sg2[64];
    __shared__ float sl[10];
    __shared__ float slse;
    const int g = blockIdx.x;
    const int t = threadIdx.x;
    const int wave = t >> 6, lane = t & 63;
    const int beg = gstart[g], end = gstart[g + 1];

    const uint32* hp = (const uint32*)h + lane;
    float a0 = 0.f, a1 = 0.f;
    for (int i = beg + wave; i < end; i += 4) {
        const uint32 w = hp[(size_t)i * 64];
        a0 += bf_lo(w); a1 += bf_hi(w);
    }
    sred[wave][lane * 2]     = a0;
    sred[wave][lane * 2 + 1] = a1;
    __syncthreads();
    if (t < FH) {
        const float s = sred[0][t] + sred[1][t] + sred[2][t] + sred[3][t];
        sred[0][t] = s / (float)max(end - beg, 1);   // gmean
    }
    __syncthreads();
    if (t < 64) {
        float acc = b4[t];
        #pragma unroll 4
        for (int k = 0; k < FH; ++k)
            acc += sred[0][k] * W4[k * 64 + t];
        sg2[t] = fmaxf(acc, 0.f);
    }
    __syncthreads();
    if (t < 10) {
        float acc = b5[t];
        #pragma unroll 4
        for (int k = 0; k < 64; ++k)
            acc += sg2[k] * W5[k * 10 + t];
        sl[t] = acc;
    }
    __syncthreads();
    if (t == 0) {
        float m = sl[0];
        #pragma unroll
        for (int j = 1; j < 10; ++j) m = fmaxf(m, sl[j]);
        float s = 0.f;
        #pragma unroll
        for (int j = 0; j < 10; ++j) s += expf(sl[j] - m);
        slse = m + logf(s);
    }
    __syncthreads();
    if (t < 10) out[g * 10 + t] = sl[t] - slse;
}

// ---------------------------------------------------------------------------
extern "C" void kernel_launch(void* const* d_in, const int* in_sizes, int n_in,
                              void* d_out, int out_size, void* d_ws, size_t ws_size,
                              hipStream_t stream) {
    const float* x     = (const float*)d_in[0];
    const int*   ei    = (const int*)d_in[1];
    const int*   batch = (const int*)d_in[2];
    const float* Wl1 = (const float*)d_in[3];
    const float* bl1 = (const float*)d_in[4];
    const float* Wr1 = (const float*)d_in[5];
    const float* Wl2 = (const float*)d_in[6];
    const float* bl2 = (const float*)d_in[7];
    const float* Wr2 = (const float*)d_in[8];
    const float* Wl3 = (const float*)d_in[9];
    const float* bl3 = (const float*)d_in[10];
    const float* Wr3 = (const float*)d_in[11];
    const float* W4  = (const float*)d_in[12];
    const float* b4  = (const float*)d_in[13];
    const float* W5  = (const float*)d_in[14];
    const float* b5  = (const float*)d_in[15];
    float* out = (float*)d_out;

    const int N = in_sizes[0] / FH;   // 50000
    const int E = in_sizes[1] / 2;    // 600000
    const int G = out_size / 10;      // 500
    const int* src = ei;
    const int* dst = ei + E;

    // ---- workspace layout (256B-aligned chunks)
    char* p = (char*)d_ws;
    auto take = [&](size_t bytes) { char* q = p; p += (bytes + 255) & ~(size_t)255; return q; };
    ushort_t* xb    = (ushort_t*)take((size_t)N * FH * 2);
    ushort_t* h     = (ushort_t*)take((size_t)N * FH * 2);
    ushort_t* aggrb = (ushort_t*)take((size_t)N * FH * 2);
    int* deg        = (int*)take((size_t)N * 4);
    int* rowptr     = (int*)take((size_t)(N + 1) * 4);
    int* pos        = (int*)take((size_t)N * 4);
    int* csr        = (int*)take((size_t)E * 4);
    int* blockSums  = (int*)take(256 * 4);
    ushort_t* Bp1   = (ushort_t*)take(256 * FH * 2);
    ushort_t* Bp2   = (ushort_t*)take(256 * FH * 2);
    ushort_t* Bp3   = (ushort_t*)take(256 * FH * 2);
    int* gstart     = (int*)take((size_t)(G + 1) * 4);

    const int nb = (N + 1023) / 1024;

    hipMemsetAsync(deg, 0, (size_t)N * 4, stream);

    // ---- prep: cvt x->bf16 + pack 3 weight sets (one kernel)
    const int cvtBlocks = (int)(((size_t)N * FH / 8 + 255) / 256);
    prep_kernel<<<cvtBlocks + 384, 256, 0, stream>>>(x, xb, (size_t)N * FH, cvtBlocks,
                                                     Wl1, Wr1, Bp1, Wl2, Wr2, Bp2, Wl3, Wr3, Bp3);

    // ---- CSR build
    deg_kernel<<<(E + 255) / 256, 256, 0, stream>>>(dst, deg, E);
    scan1_kernel<<<nb, 256, 0, stream>>>(deg, rowptr, blockSums, N);
    scan2_kernel<<<1, 64, 0, stream>>>(blockSums, rowptr, nb, N);
    scan3_kernel<<<nb, 256, 0, stream>>>(rowptr, pos, blockSums, N);
    fill_csr_kernel<<<(E + 255) / 256, 256, 0, stream>>>(src, dst, pos, csr, E);

    // ---- group bounds from sorted batch
    group_bounds_kernel<<<(G + 256) / 256, 256, 0, stream>>>(batch, gstart, N, G);

    const int pullGrid = (N * 64 + 255) / 256;   // one wave per node
    const int gemmGrid = (N + 63) / 64;

    // ---- 3 SAGE layers (split pull + MFMA; sage is in-place safe)
    pull_mean_kernel<<<pullGrid, 256, 0, stream>>>(xb, rowptr, csr, aggrb, N);
    sage_mfma_kernel<<<gemmGrid, 256, 0, stream>>>(xb, aggrb, Bp1, bl1, h, N);

    pull_mean_kernel<<<pullGrid, 256, 0, stream>>>(h, rowptr, csr, aggrb, N);
    sage_mfma_kernel<<<gemmGrid, 256, 0, stream>>>(h, aggrb, Bp2, bl2, h, N);

    pull_mean_kernel<<<pullGrid, 256, 0, stream>>>(h, rowptr, csr, aggrb, N);
    sage_mfma_kernel<<<gemmGrid, 256, 0, stream>>>(h, aggrb, Bp3, bl3, h, N);

    // ---- fused head (pool + MLP + log_softmax)
    head_kernel<<<G, 256, 0, stream>>>(h, gstart, W4, b4, W5, b5, out, G);
}

// Round 7
// 219.562 us; speedup vs baseline: 1.6368x; 1.1063x over previous
//
#include <hip/hip_runtime.h>
#include <hip/hip_bf16.h>
#include <math.h>

#define FH 128   // feature width of x and all hidden layers

typedef __attribute__((ext_vector_type(8))) short short8v;   // 8 bf16 (4 VGPRs)
typedef __attribute__((ext_vector_type(4))) float float4v;
typedef unsigned short ushort_t;
typedef unsigned int   uint32;

__device__ __forceinline__ ushort_t f2bf(float f) {          // RNE float->bf16
    uint32 u = __builtin_bit_cast(uint32, f);
    u += 0x7fffu + ((u >> 16) & 1u);
    return (ushort_t)(u >> 16);
}
__device__ __forceinline__ float bf_lo(uint32 w) { return __builtin_bit_cast(float, w << 16); }
__device__ __forceinline__ float bf_hi(uint32 w) { return __builtin_bit_cast(float, w & 0xffff0000u); }
__device__ __forceinline__ uint32 pack2(float lo, float hi) {
    return (uint32)f2bf(lo) | ((uint32)f2bf(hi) << 16);
}

// ---------------------------------------------------------------------------
// pack: Bp[((nt*8+kt)*64 + lane)*8 + j] = W[k][n],
//   nt=n>>4, kt=k>>5, lane=(n&15)+16*((k>>3)&3), j=k&7   (W = [Wl;Wr], 256x128)
__device__ __forceinline__ void pack_one(const float* __restrict__ Wl,
                                         const float* __restrict__ Wr,
                                         ushort_t* __restrict__ Bp, int t) {
    int k = t >> 7, n = t & 127;
    float v = (k < FH) ? Wl[k * FH + n] : Wr[(k - FH) * FH + n];
    int nt = n >> 4, kt = k >> 5;
    int lane = (n & 15) + (((k >> 3) & 3) << 4);
    int j = k & 7;
    Bp[(((nt * 8 + kt) * 64) + lane) * 8 + j] = f2bf(v);
}

// fused prep: cvt x->bf16 | 3 weight packs | deg count | group bounds
__global__ __launch_bounds__(256) void fused_prep_kernel(
        const float* __restrict__ x, ushort_t* __restrict__ xb, size_t n, int cvtBlocks,
        const float* __restrict__ Wl1, const float* __restrict__ Wr1, ushort_t* __restrict__ Bp1,
        const float* __restrict__ Wl2, const float* __restrict__ Wr2, ushort_t* __restrict__ Bp2,
        const float* __restrict__ Wl3, const float* __restrict__ Wr3, ushort_t* __restrict__ Bp3,
        const int* __restrict__ dst, int* __restrict__ deg, int E, int degBlocks,
        const int* __restrict__ batch, int* __restrict__ gstart, int N, int G) {
    int b = blockIdx.x;
    if (b < cvtBlocks) {
        size_t base = ((size_t)b * 256 + threadIdx.x) * 8;
        if (base >= n) return;
        const float4 a = *(const float4*)(x + base);
        const float4 c = *(const float4*)(x + base + 4);
        ushort_t o[8] = {f2bf(a.x), f2bf(a.y), f2bf(a.z), f2bf(a.w),
                         f2bf(c.x), f2bf(c.y), f2bf(c.z), f2bf(c.w)};
        *(uint4*)(xb + base) = *(const uint4*)o;
        return;
    }
    b -= cvtBlocks;
    if (b < 384) {                               // weight packs
        int which = b >> 7;
        int t = (b & 127) * 256 + threadIdx.x;
        if (which == 0)      pack_one(Wl1, Wr1, Bp1, t);
        else if (which == 1) pack_one(Wl2, Wr2, Bp2, t);
        else                 pack_one(Wl3, Wr3, Bp3, t);
        return;
    }
    b -= 384;
    if (b < degBlocks) {                         // in-degree count
        int e = b * 256 + threadIdx.x;
        if (e < E) atomicAdd(&deg[dst[e]], 1);
        return;
    }
    b -= degBlocks;
    {                                            // group bounds (sorted batch)
        int g = b * 256 + threadIdx.x;
        if (g > G) return;
        int lo = 0, hi = N;
        while (lo < hi) {
            int mid = (lo + hi) >> 1;
            if (batch[mid] < g) lo = mid + 1; else hi = mid;
        }
        gstart[g] = lo;
    }
}

// ---------------------------------------------------------------------------
// CSR build
__global__ __launch_bounds__(256) void scan1_kernel(const int* __restrict__ deg,
                                                    int* __restrict__ rowptr,
                                                    int* __restrict__ blockSums, int N) {
    __shared__ int lds[256];
    const int base = blockIdx.x * 1024;
    const int t = threadIdx.x;
    int v[4]; int sum = 0;
    #pragma unroll
    for (int j = 0; j < 4; ++j) {
        int idx = base + t * 4 + j;
        v[j] = (idx < N) ? deg[idx] : 0;
        sum += v[j];
    }
    lds[t] = sum; __syncthreads();
    for (int off = 1; off < 256; off <<= 1) {
        int val = lds[t];
        int add = (t >= off) ? lds[t - off] : 0;
        __syncthreads();
        lds[t] = val + add;
        __syncthreads();
    }
    int run = (t > 0) ? lds[t - 1] : 0;
    #pragma unroll
    for (int j = 0; j < 4; ++j) {
        int idx = base + t * 4 + j;
        if (idx < N) rowptr[idx] = run;
        run += v[j];
    }
    if (t == 255) blockSums[blockIdx.x] = lds[255];
}

__global__ void scan2_kernel(int* __restrict__ blockSums, int* __restrict__ rowptr,
                             int nb, int N) {
    if (threadIdx.x == 0 && blockIdx.x == 0) {
        int carry = 0;
        for (int i = 0; i < nb; ++i) {
            int s = blockSums[i];
            blockSums[i] = carry;
            carry += s;
        }
        rowptr[N] = carry;   // == E
    }
}

// adds block offset AND writes pos[] (atomic cursor copy) in one pass
__global__ __launch_bounds__(256) void scan3_kernel(int* __restrict__ rowptr,
                                                    int* __restrict__ pos,
                                                    const int* __restrict__ blockSums, int N) {
    const int base = blockIdx.x * 1024;
    const int add = blockSums[blockIdx.x];
    #pragma unroll
    for (int j = 0; j < 4; ++j) {
        int idx = base + threadIdx.x * 4 + j;
        if (idx < N) {
            int v = rowptr[idx] + add;
            rowptr[idx] = v;
            pos[idx] = v;
        }
    }
}

__global__ __launch_bounds__(256) void fill_csr_kernel(const int* __restrict__ src,
                                                       const int* __restrict__ dst,
                                                       int* __restrict__ pos,
                                                       int* __restrict__ csr, int E) {
    int e = blockIdx.x * 256 + threadIdx.x;
    if (e >= E) return;
    int idx = atomicAdd(&pos[dst[e]], 1);
    csr[idx] = src[e];
}

// ---------------------------------------------------------------------------
// pull aggregation (bf16 in/out, fp32 accumulate): one wave per dst node.
// 4-deep predicated prologue: 4 csr loads then 4 independent 256B row loads
// in flight per 16-lane group set (covers deg<=16 without looping).
__global__ __launch_bounds__(256) void pull_mean_kernel(const ushort_t* __restrict__ x,
                                                        const int* __restrict__ rowptr,
                                                        const int* __restrict__ csr,
                                                        ushort_t* __restrict__ aggr, int N) {
    const int v = (blockIdx.x * 256 + threadIdx.x) >> 6;
    if (v >= N) return;
    const int lane = threadIdx.x & 63;
    const int grp  = lane >> 4;        // which of 4 concurrent edges
    const int li   = lane & 15;        // uint4 column within the row
    const int beg = rowptr[v], end = rowptr[v + 1];
    const uint4* xp = (const uint4*)x + li;    // row = 16 uint4 (256B)

    const uint4 z = {0u, 0u, 0u, 0u};
    uint4 w0 = z, w1 = z, w2 = z, w3 = z;
    const int i0 = beg + grp;
    if (i0 < end)      w0 = xp[(size_t)csr[i0] * 16];
    if (i0 + 4 < end)  w1 = xp[(size_t)csr[i0 + 4] * 16];
    if (i0 + 8 < end)  w2 = xp[(size_t)csr[i0 + 8] * 16];
    if (i0 + 12 < end) w3 = xp[(size_t)csr[i0 + 12] * 16];

    float a0 = (bf_lo(w0.x) + bf_lo(w1.x)) + (bf_lo(w2.x) + bf_lo(w3.x));
    float a1 = (bf_hi(w0.x) + bf_hi(w1.x)) + (bf_hi(w2.x) + bf_hi(w3.x));
    float a2 = (bf_lo(w0.y) + bf_lo(w1.y)) + (bf_lo(w2.y) + bf_lo(w3.y));
    float a3 = (bf_hi(w0.y) + bf_hi(w1.y)) + (bf_hi(w2.y) + bf_hi(w3.y));
    float a4 = (bf_lo(w0.z) + bf_lo(w1.z)) + (bf_lo(w2.z) + bf_lo(w3.z));
    float a5 = (bf_hi(w0.z) + bf_hi(w1.z)) + (bf_hi(w2.z) + bf_hi(w3.z));
    float a6 = (bf_lo(w0.w) + bf_lo(w1.w)) + (bf_lo(w2.w) + bf_lo(w3.w));
    float a7 = (bf_hi(w0.w) + bf_hi(w1.w)) + (bf_hi(w2.w) + bf_hi(w3.w));

    for (int i = beg + 16 + grp; i < end; i += 4) {   // rare tail (deg > 16)
        const uint4 w = xp[(size_t)csr[i] * 16];
        a0 += bf_lo(w.x); a1 += bf_hi(w.x); a2 += bf_lo(w.y); a3 += bf_hi(w.y);
        a4 += bf_lo(w.z); a5 += bf_hi(w.z); a6 += bf_lo(w.w); a7 += bf_hi(w.w);
    }

    // combine the 4 group partials
    a0 += __shfl_xor(a0, 16); a1 += __shfl_xor(a1, 16);
    a2 += __shfl_xor(a2, 16); a3 += __shfl_xor(a3, 16);
    a4 += __shfl_xor(a4, 16); a5 += __shfl_xor(a5, 16);
    a6 += __shfl_xor(a6, 16); a7 += __shfl_xor(a7, 16);
    a0 += __shfl_xor(a0, 32); a1 += __shfl_xor(a1, 32);
    a2 += __shfl_xor(a2, 32); a3 += __shfl_xor(a3, 32);
    a4 += __shfl_xor(a4, 32); a5 += __shfl_xor(a5, 32);
    a6 += __shfl_xor(a6, 32); a7 += __shfl_xor(a7, 32);

    if (grp == 0) {
        const float inv = 1.0f / (float)max(end - beg, 1);
        uint4 o;
        o.x = pack2(a0 * inv, a1 * inv);
        o.y = pack2(a2 * inv, a3 * inv);
        o.z = pack2(a4 * inv, a5 * inv);
        o.w = pack2(a6 * inv, a7 * inv);
        ((uint4*)aggr)[(size_t)v * 16 + li] = o;
    }
}

// ---------------------------------------------------------------------------
// fused SAGE layer via MFMA: out = relu([aggr|xin](Mx256) @ W(256x128) + bl)
// 4 waves/block, 16 rows/wave; weights in 64KB LDS. After the MFMA loop the
// LDS is re-used (barrier-protected) as a per-wave output staging tile so
// global stores are fully-coalesced 1KB uint4 rows. In-place safe.
#define SO_STRIDE 136   // ushorts per staged row (16B-aligned, bank-spread)
__global__ __launch_bounds__(256) void sage_mfma_kernel(const ushort_t* __restrict__ xin,
                                                        const ushort_t* __restrict__ aggr,
                                                        const ushort_t* __restrict__ Bp,
                                                        const float* __restrict__ bl,
                                                        ushort_t* __restrict__ out, int M) {
    __shared__ ushort_t sB[32768];   // 64 KB
    const int tid = threadIdx.x;
    {   // cooperative 64KB load: 4096 x 16B
        const uint4* s = (const uint4*)Bp;
        uint4* d = (uint4*)sB;
        #pragma unroll
        for (int i = 0; i < 16; ++i)
            d[tid + 256 * i] = s[tid + 256 * i];
    }
    __syncthreads();

    const int wave = tid >> 6;
    const int lane = tid & 63;
    const int grp  = lane >> 4;
    const int li   = lane & 15;
    const int rowBase = (blockIdx.x * 4 + wave) * 16;
    const int arow = min(rowBase + li, M - 1);

    short8v afrag[8];
    #pragma unroll
    for (int kt = 0; kt < 4; ++kt)
        afrag[kt] = *(const short8v*)(aggr + (size_t)arow * FH + kt * 32 + grp * 8);
    #pragma unroll
    for (int kt = 0; kt < 4; ++kt)
        afrag[4 + kt] = *(const short8v*)(xin + (size_t)arow * FH + kt * 32 + grp * 8);

    float4v acc[8];
    #pragma unroll
    for (int nt = 0; nt < 8; ++nt) {
        acc[nt] = (float4v){0.f, 0.f, 0.f, 0.f};
        #pragma unroll
        for (int kt = 0; kt < 8; ++kt) {
            const short8v b = *(const short8v*)(sB + (((nt * 8 + kt) * 64) + lane) * 8);
            acc[nt] = __builtin_amdgcn_mfma_f32_16x16x32_bf16(afrag[kt], b, acc[nt], 0, 0, 0);
        }
    }

    __syncthreads();   // all waves finished reading sB; re-use it as sOut

    // stage bf16 outputs: wave-private [16][SO_STRIDE] region
    ushort_t* so = sB + wave * (16 * SO_STRIDE);
    #pragma unroll
    for (int nt = 0; nt < 8; ++nt) {
        const float bias = bl[nt * 16 + li];
        #pragma unroll
        for (int r = 0; r < 4; ++r)
            so[(grp * 4 + r) * SO_STRIDE + nt * 16 + li] = f2bf(fmaxf(acc[nt][r] + bias, 0.f));
    }
    // wave-private region: no barrier needed (compiler inserts lgkmcnt wait)
    #pragma unroll
    for (int t = 0; t < 4; ++t) {
        const int idx = lane + 64 * t;       // 0..255
        const int r  = idx >> 4;             // staged row 0..15
        const int ch = idx & 15;             // uint4 chunk within the row
        const int row = rowBase + r;
        if (row < M) {
            const uint4 val = *(const uint4*)(so + r * SO_STRIDE + ch * 8);
            *(uint4*)(out + (size_t)row * FH + ch * 8) = val;
        }
    }
}

// ---------------------------------------------------------------------------
// fused head: per-group mean pool -> relu(gmean@W4+b4) -> log_softmax(g2@W5+b5)
__global__ __launch_bounds__(256) void head_kernel(const ushort_t* __restrict__ h,
                                                   const int* __restrict__ gstart,
                                                   const float* __restrict__ W4,
                                                   const float* __restrict__ b4,
                                                   const float* __restrict__ W5,
                                                   const float* __restrict__ b5,
                                                   float* __restrict__ out, int G) {
    __shared__ float sred[4][FH];
    __shared__ float sg2[64];
    __shared__ float sl[10];
    __shared__ float slse;
    const int g = blockIdx.x;
    const int t = threadIdx.x;
    const int wave = t >> 6, lane = t & 63;
    const int beg = gstart[g], end = gstart[g + 1];

    const uint32* hp = (const uint32*)h + lane;
    float a0 = 0.f, a1 = 0.f;
    for (int i = beg + wave; i < end; i += 4) {
        const uint32 w = hp[(size_t)i * 64];
        a0 += bf_lo(w); a1 += bf_hi(w);
    }
    sred[wave][lane * 2]     = a0;
    sred[wave][lane * 2 + 1] = a1;
    __syncthreads();
    if (t < FH) {
        const float s = sred[0][t] + sred[1][t] + sred[2][t] + sred[3][t];
        sred[0][t] = s / (float)max(end - beg, 1);   // gmean
    }
    __syncthreads();
    if (t < 64) {
        float acc = b4[t];
        #pragma unroll 4
        for (int k = 0; k < FH; ++k)
            acc += sred[0][k] * W4[k * 64 + t];
        sg2[t] = fmaxf(acc, 0.f);
    }
    __syncthreads();
    if (t < 10) {
        float acc = b5[t];
        #pragma unroll 4
        for (int k = 0; k < 64; ++k)
            acc += sg2[k] * W5[k * 10 + t];
        sl[t] = acc;
    }
    __syncthreads();
    if (t == 0) {
        float m = sl[0];
        #pragma unroll
        for (int j = 1; j < 10; ++j) m = fmaxf(m, sl[j]);
        float s = 0.f;
        #pragma unroll
        for (int j = 0; j < 10; ++j) s += expf(sl[j] - m);
        slse = m + logf(s);
    }
    __syncthreads();
    if (t < 10) out[g * 10 + t] = sl[t] - slse;
}

// ---------------------------------------------------------------------------
extern "C" void kernel_launch(void* const* d_in, const int* in_sizes, int n_in,
                              void* d_out, int out_size, void* d_ws, size_t ws_size,
                              hipStream_t stream) {
    const float* x     = (const float*)d_in[0];
    const int*   ei    = (const int*)d_in[1];
    const int*   batch = (const int*)d_in[2];
    const float* Wl1 = (const float*)d_in[3];
    const float* bl1 = (const float*)d_in[4];
    const float* Wr1 = (const float*)d_in[5];
    const float* Wl2 = (const float*)d_in[6];
    const float* bl2 = (const float*)d_in[7];
    const float* Wr2 = (const float*)d_in[8];
    const float* Wl3 = (const float*)d_in[9];
    const float* bl3 = (const float*)d_in[10];
    const float* Wr3 = (const float*)d_in[11];
    const float* W4  = (const float*)d_in[12];
    const float* b4  = (const float*)d_in[13];
    const float* W5  = (const float*)d_in[14];
    const float* b5  = (const float*)d_in[15];
    float* out = (float*)d_out;

    const int N = in_sizes[0] / FH;   // 50000
    const int E = in_sizes[1] / 2;    // 600000
    const int G = out_size / 10;      // 500
    const int* src = ei;
    const int* dst = ei + E;

    // ---- workspace layout (256B-aligned chunks)
    char* p = (char*)d_ws;
    auto take = [&](size_t bytes) { char* q = p; p += (bytes + 255) & ~(size_t)255; return q; };
    ushort_t* xb    = (ushort_t*)take((size_t)N * FH * 2);
    ushort_t* h     = (ushort_t*)take((size_t)N * FH * 2);
    ushort_t* aggrb = (ushort_t*)take((size_t)N * FH * 2);
    int* deg        = (int*)take((size_t)N * 4);
    int* rowptr     = (int*)take((size_t)(N + 1) * 4);
    int* pos        = (int*)take((size_t)N * 4);
    int* csr        = (int*)take((size_t)E * 4);
    int* blockSums  = (int*)take(256 * 4);
    ushort_t* Bp1   = (ushort_t*)take(256 * FH * 2);
    ushort_t* Bp2   = (ushort_t*)take(256 * FH * 2);
    ushort_t* Bp3   = (ushort_t*)take(256 * FH * 2);
    int* gstart     = (int*)take((size_t)(G + 1) * 4);

    const int nb = (N + 1023) / 1024;

    hipMemsetAsync(deg, 0, (size_t)N * 4, stream);

    // ---- fused prep: cvt + packs + deg count + group bounds
    const int cvtBlocks = (int)(((size_t)N * FH / 8 + 255) / 256);
    const int degBlocks = (E + 255) / 256;
    const int gbBlocks  = (G + 1 + 255) / 256;
    fused_prep_kernel<<<cvtBlocks + 384 + degBlocks + gbBlocks, 256, 0, stream>>>(
        x, xb, (size_t)N * FH, cvtBlocks,
        Wl1, Wr1, Bp1, Wl2, Wr2, Bp2, Wl3, Wr3, Bp3,
        dst, deg, E, degBlocks,
        batch, gstart, N, G);

    // ---- CSR build
    scan1_kernel<<<nb, 256, 0, stream>>>(deg, rowptr, blockSums, N);
    scan2_kernel<<<1, 64, 0, stream>>>(blockSums, rowptr, nb, N);
    scan3_kernel<<<nb, 256, 0, stream>>>(rowptr, pos, blockSums, N);
    fill_csr_kernel<<<(E + 255) / 256, 256, 0, stream>>>(src, dst, pos, csr, E);

    const int pullGrid = (N * 64 + 255) / 256;   // one wave per node
    const int gemmGrid = (N + 63) / 64;

    // ---- 3 SAGE layers (split pull + MFMA; sage is in-place safe)
    pull_mean_kernel<<<pullGrid, 256, 0, stream>>>(xb, rowptr, csr, aggrb, N);
    sage_mfma_kernel<<<gemmGrid, 256, 0, stream>>>(xb, aggrb, Bp1, bl1, h, N);

    pull_mean_kernel<<<pullGrid, 256, 0, stream>>>(h, rowptr, csr, aggrb, N);
    sage_mfma_kernel<<<gemmGrid, 256, 0, stream>>>(h, aggrb, Bp2, bl2, h, N);

    pull_mean_kernel<<<pullGrid, 256, 0, stream>>>(h, rowptr, csr, aggrb, N);
    sage_mfma_kernel<<<gemmGrid, 256, 0, stream>>>(h, aggrb, Bp3, bl3, h, N);

    // ---- fused head (pool + MLP + log_softmax)
    head_kernel<<<G, 256, 0, stream>>>(h, gstart, W4, b4, W5, b5, out, G);
}